// Round 1
// baseline (16657.452 us; speedup 1.0000x reference)
//
#include <hip/hip_runtime.h>
#include <hip/hip_bf16.h>
#include <stdint.h>

typedef unsigned short u16;
typedef unsigned int   u32;
typedef __attribute__((ext_vector_type(4)))  int   i32x4;
typedef __attribute__((ext_vector_type(4)))  float f32x4;
typedef __attribute__((ext_vector_type(16))) float f32x16;
typedef __attribute__((ext_vector_type(8)))  u16   u16x8;

typedef __attribute__((address_space(3))) char  as3_char;
typedef __attribute__((address_space(3))) float as3_f32;
typedef __attribute__((address_space(3))) i32x4 as3_i32x4;
typedef __attribute__((address_space(3))) void  as3_void;
typedef __attribute__((address_space(1))) const void as1_cvoid;

#define B_    64
#define T_    512
#define DIN_  512
#define H_    1024
#define NBLK_ 128
#define NTHR_ 512

#define OUT_MAIN_ (64ull*512*1024)
#define HN_BASE_  OUT_MAIN_
#define CN_BASE_  (OUT_MAIN_ + 2ull*64*1024)

// ---- workspace layout (bytes) ----
#define WB0_OFF  0ull
#define WB0_SZ   (64ull*64*1536*2)        // 12.6 MB  layer0 weights bf16, [grp][col][K]
#define WB1_OFF  (WB0_OFF + WB0_SZ)
#define WB1_SZ   (64ull*64*2048*2)        // 16.8 MB  layer1
#define XT_OFF   (WB1_OFF + WB1_SZ)
#define XT_SZ    (512ull*64*512*2)        // 32 MB    x as bf16, [t][b][d]
#define H0_OFF   (XT_OFF + XT_SZ)
#define HBUF_SZ  (64ull*1024*2)           // 128 KB per h buffer
#define H1_OFF   (H0_OFF + 2*HBUF_SZ)
#define BIAS_OFF (H1_OFF + 2*HBUF_SZ)
#define BIAS_SZ  (2ull*4096*4)
#define CNT_OFF  (BIAS_OFF + BIAS_SZ)

__device__ __forceinline__ u16 f2bf(float f) {   // RNE fp32 -> bf16
  u32 u = __builtin_bit_cast(u32, f);
  return (u16)((u + 0x7FFFu + ((u >> 16) & 1u)) >> 16);
}
__device__ __forceinline__ float sigf(float x) {
  float e = __builtin_amdgcn_exp2f(x * -1.442695041f);
  return __builtin_amdgcn_rcpf(1.0f + e);
}
__device__ __forceinline__ float tanhf_fast(float x) {
  float e = __builtin_amdgcn_exp2f(x * -2.885390082f);
  float r = __builtin_amdgcn_rcpf(1.0f + e);
  return fmaf(2.0f, r, -1.0f);
}

// ============================ prep kernels ============================

__global__ void prep_misc(const float* __restrict__ bih0, const float* __restrict__ bhh0,
                          const float* __restrict__ bih1, const float* __restrict__ bhh1,
                          float* __restrict__ bias, u32* __restrict__ hz,
                          unsigned* __restrict__ cnt)
{
  int i = blockIdx.x * 256 + threadIdx.x;
  if (i < 4096) bias[i] = bih0[i] + bhh0[i];
  else if (i < 8192) bias[i] = bih1[i - 4096] + bhh1[i - 4096];
  if (i < 131072) hz[i] = 0u;              // zero all 4 h buffers (512 KB)
  if (i == 0) *cnt = 0u;
}

// transpose-gather weights: W[k][n] fp32 -> Wb[grp][col][K] bf16 (col-major slices)
__global__ void prep_w(const float* __restrict__ Wih0, const float* __restrict__ Whh0,
                       const float* __restrict__ Wih1, const float* __restrict__ Whh1,
                       u16* __restrict__ Wb0, u16* __restrict__ Wb1)
{
  __shared__ u16 tile[64][72];
  const int bid = blockIdx.x;
  const int layer = (bid >= 1536) ? 1 : 0;
  const int lb = layer ? bid - 1536 : bid;
  const int nkt = layer ? 32 : 24;
  const int kt = lb % nkt, nt = lb / nkt;
  const int K = layer ? 2048 : 1536;
  const int xlen = layer ? 1024 : 512;
  const float* Wih = layer ? Wih1 : Wih0;
  const float* Whh = layer ? Whh1 : Whh0;
  u16* Wb = layer ? Wb1 : Wb0;
  const int k0 = kt * 64, n0 = nt * 64;
  const int t = threadIdx.x;
  {
    int kr = t >> 2, ncs = (t & 3) * 16;
    int kk = k0 + kr;
    const float* src = (kk < xlen) ? (Wih + (size_t)kk * 4096)
                                   : (Whh + (size_t)(kk - xlen) * 4096);
    const float* p = src + n0 + ncs;
#pragma unroll
    for (int v = 0; v < 4; ++v) {
      f32x4 f = *(const f32x4*)(p + v * 4);
#pragma unroll
      for (int e = 0; e < 4; ++e) tile[kr][ncs + v*4 + e] = f2bf(f[e]);
    }
  }
  __syncthreads();
  {
    int c = t >> 2;
    int n = n0 + c;
    int gate = n >> 10, hcol = n & 1023;
    int grp = hcol >> 4, cd = gate * 16 + (hcol & 15);
    u16* dstc = Wb + ((size_t)(grp * 64 + cd) * K + k0);
#pragma unroll
    for (int kv = 0; kv < 2; ++kv) {
      int k8 = (t & 3) + 4 * kv;
      u16x8 vv;
#pragma unroll
      for (int e = 0; e < 8; ++e) vv[e] = tile[k8*8 + e][c];
      *(u16x8*)(dstc + k8 * 8) = vv;
    }
  }
}

// x [b][t][d] fp32 -> xT [t][b][d] bf16
__global__ void prep_x(const float* __restrict__ x, u16* __restrict__ xT)
{
  int i = blockIdx.x * 256 + threadIdx.x;      // 1,048,576 total
  int d16 = (i & 31) << 4;
  int b   = (i >> 5) & 63;
  int tt  = i >> 11;
  const float* s = x + ((size_t)b * T_ + tt) * DIN_ + d16;
  u16* d = xT + ((size_t)tt * B_ + b) * DIN_ + d16;
  f32x4 fa = *(const f32x4*)(s);
  f32x4 fb = *(const f32x4*)(s + 4);
  f32x4 fc = *(const f32x4*)(s + 8);
  f32x4 fd = *(const f32x4*)(s + 12);
  u16x8 o0, o1;
#pragma unroll
  for (int e = 0; e < 4; ++e) {
    o0[e] = f2bf(fa[e]); o0[4+e] = f2bf(fb[e]);
    o1[e] = f2bf(fc[e]); o1[4+e] = f2bf(fd[e]);
  }
  *(u16x8*)d = o0;
  *(u16x8*)(d + 8) = o1;
}

// ============================ persistent LSTM kernel ============================
// 128 blocks x 512 threads. Blocks 0..63: layer0 (t=s). Blocks 64..127: layer1 (t=s-1).
// Block owns 16 h-cols (64 gate-cols). 8 waves = 2 col-jobs x 4-way K-split.
// Wave job: C[64 x 32], K/4 slice, 32x32x16 bf16 MFMA; B via LDS (swizzled),
// A via sc0/sc1 global->reg ring (device-coherent, L2 untouched -> weights stay L2-resident).

template<int LAYER>
__device__ __forceinline__ void run_phase(
    const int t, const int lane, const int w, const int grp,
    const u16* __restrict__ xt, const u16* __restrict__ Wb,
    const u16* __restrict__ h0r, const u16* __restrict__ h1p,
    u16* __restrict__ hw,
    const float b0, const float b1, const float b2, const float b3,
    float (&cst)[2], float* __restrict__ out, as3_char* ldsb)
{
  constexpr int K   = LAYER ? 2048 : 1536;
  constexpr int NCH = LAYER ? 4 : 3;          // 128-wide K chunks per quarter
  constexpr int Kq  = K / 4;
  const int nj = w >> 2, q = w & 3;
  const int c4  = lane >> 4;
  const int m15 = lane & 15;
  const int arow = lane & 31, ahi = lane >> 5;
  const int sk_e = (m15 * 16) ^ (c4 << 4);          // pre-swizzled stage offsets
  const int sk_o = (m15 * 16) ^ ((4 + c4) << 4);
  const int rc   = lane & 31;
  const int rswz = (rc & 7) << 4;
  as3_char* myLds = ldsb + w * 16384;
  const u16* WbJob = Wb + (size_t)(nj * 32) * K;

  f32x16 acc0 = {}; f32x16 acc1 = {};
  i32x4 ring[2][8][2];

  auto stageB = [&](int i) {
    as3_char* dst0 = myLds + (i & 1) * 8192;
    int kabs = q * Kq + i * 128;
    const char* gb = (const char*)WbJob;
#pragma unroll
    for (int j = 0; j < 8; ++j) {
      int cl = 4 * j + c4;
      int koffb = (j & 1) ? sk_o : sk_e;
      const char* g = gb + ((size_t)cl * K + kabs) * 2 + koffb;
      __builtin_amdgcn_global_load_lds((as1_cvoid*)g, (as3_void*)(dst0 + j * 1024), 16, 0, 0);
    }
  };

  auto loadA = [&](int i) {
    int kabs = q * Kq + i * 128;
    const u16* sp; int rs, kloc;
    if (LAYER == 0) {
      if (kabs < 512) { sp = xt;  rs = 512;  kloc = kabs; }
      else            { sp = h0r; rs = 1024; kloc = kabs - 512; }
    } else {
      if (kabs < 1024){ sp = h0r; rs = 1024; kloc = kabs; }
      else            { sp = h1p; rs = 1024; kloc = kabs - 1024; }
    }
    const char* base = (const char*)sp;
    size_t lane_off = ((size_t)arow * rs + (size_t)ahi * 8) * 2;
#pragma unroll
    for (int kk = 0; kk < 8; ++kk) {
#pragma unroll
      for (int f = 0; f < 2; ++f) {
        uint64_t addr = (uint64_t)(base + lane_off + ((size_t)(32 * f) * rs + kloc + kk * 16) * 2);
        asm volatile("global_load_dwordx4 %0, %1, off sc0 sc1"
                     : "=&v"(ring[i & 1][kk][f]) : "v"(addr));
      }
    }
  };

  stageB(0); loadA(0);
#pragma unroll
  for (int i = 0; i < NCH; ++i) {
    if (i + 1 < NCH) {
      stageB(i + 1); loadA(i + 1);
      asm volatile("s_waitcnt vmcnt(24)" ::: "memory");   // drain chunk i (B+A), keep i+1 in flight
    } else {
      asm volatile("s_waitcnt vmcnt(0)" ::: "memory");
    }
    __builtin_amdgcn_sched_barrier(0);
    as3_char* buf = myLds + (i & 1) * 8192;
#pragma unroll
    for (int kk = 0; kk < 8; ++kk) {
      int off = (rc << 8) + (((kk << 5) | (ahi << 4)) ^ rswz);
      i32x4 b = *(as3_i32x4*)(buf + off);
      asm("v_mfma_f32_32x32x16_bf16 %0, %1, %2, %0" : "+v"(acc0) : "v"(ring[i & 1][kk][0]), "v"(b));
      asm("v_mfma_f32_32x32x16_bf16 %0, %1, %2, %0" : "+v"(acc1) : "v"(ring[i & 1][kk][1]), "v"(b));
    }
  }

  // ---- cross-wave K reduction via LDS (reuse B buffers) ----
  __syncthreads();
  as3_f32* accb = (as3_f32*)ldsb;              // [job*4+q][64][33]
#pragma unroll
  for (int f = 0; f < 2; ++f) {
#pragma unroll
    for (int r = 0; r < 16; ++r) {
      int row = 32 * f + (r & 3) + 8 * (r >> 2) + 4 * ahi;
      float v = (f == 0) ? acc0[r] : acc1[r];
      accb[((nj * 4 + q) * 64 + row) * 33 + rc] = v;
    }
  }
  __syncthreads();

  // ---- cell update: 8 rows per wave, 16 h-cols, 2 elems/lane ----
  const int hc = m15;
  const int colg = grp * 16 + hc;
#pragma unroll
  for (int e = 0; e < 2; ++e) {
    int row = w * 8 + (lane >> 4) + 4 * e;
    float g[4];
#pragma unroll
    for (int gt = 0; gt < 4; ++gt) {
      int jb = gt >> 1, col = (gt & 1) * 16 + hc;
      float v = 0.f;
#pragma unroll
      for (int qq = 0; qq < 4; ++qq) v += accb[((jb * 4 + qq) * 64 + row) * 33 + col];
      g[gt] = v;
    }
    float ig = sigf(g[0] + b0);
    float fg = sigf(g[1] + b1);
    float cg = fmaxf(g[2] + b2, 0.0f);
    float og = sigf(g[3] + b3);
    float cn = fg * cst[e] + ig * cg;
    cst[e] = cn;
    float h = og * tanhf_fast(cn);

    u32 hbv = (u32)f2bf(h);
    uint64_t ha = (uint64_t)((const char*)hw + ((size_t)row * H_ + colg) * 2);
    asm volatile("global_store_short %0, %1, off sc0 sc1" :: "v"(ha), "v"(hbv) : "memory");
    if (LAYER == 1) out[((size_t)row * T_ + t) * H_ + colg] = h;
    if (t == T_ - 1) {
      out[HN_BASE_ + ((size_t)LAYER * 64 + row) * H_ + colg] = h;
      out[CN_BASE_ + ((size_t)LAYER * 64 + row) * H_ + colg] = cn;
    }
  }
}

__global__ __launch_bounds__(NTHR_) void lstm_persist(
    const u16* __restrict__ xT, const u16* __restrict__ Wb0, const u16* __restrict__ Wb1,
    u16* __restrict__ h0buf, u16* __restrict__ h1buf, const float* __restrict__ bias,
    unsigned* __restrict__ cnt, float* __restrict__ out)
{
  __shared__ char ldsRaw[131072];
  as3_char* ldsb = (as3_char*)ldsRaw;
  const int tid = threadIdx.x, lane = tid & 63, w = tid >> 6;
  const int bid = blockIdx.x;
  const int layer = bid >> 6, grp = bid & 63;
  const u16* Wb = layer ? (Wb1 + (size_t)grp * 64 * 2048) : (Wb0 + (size_t)grp * 64 * 1536);
  float b0, b1, b2, b3;
  {
    int colg = grp * 16 + (lane & 15);
    const float* bb = bias + layer * 4096;
    b0 = bb[colg]; b1 = bb[1024 + colg]; b2 = bb[2048 + colg]; b3 = bb[3072 + colg];
  }
  float cst[2] = {0.f, 0.f};

  for (int s = 0; s <= T_; ++s) {
    if (layer == 0) {
      if (s < T_) {
        const u16* h0r = h0buf + ((size_t)((s + 1) & 1)) * (B_ * H_);
        u16* hwp = h0buf + ((size_t)(s & 1)) * (B_ * H_);
        run_phase<0>(s, lane, w, grp, xT + (size_t)s * B_ * DIN_, Wb,
                     h0r, nullptr, hwp, b0, b1, b2, b3, cst, out, ldsb);
      }
    } else {
      if (s >= 1) {
        int t = s - 1;
        const u16* h0r = h0buf + ((size_t)((s + 1) & 1)) * (B_ * H_);
        const u16* h1p = h1buf + ((size_t)(s & 1)) * (B_ * H_);
        u16* hwp = h1buf + ((size_t)((s + 1) & 1)) * (B_ * H_);
        run_phase<1>(t, lane, w, grp, nullptr, Wb,
                     h0r, h1p, hwp, b0, b1, b2, b3, cst, out, ldsb);
      }
    }
    // ---- grid barrier (monotonic counter, agent scope; no L2 invalidation) ----
    __syncthreads();                              // drains vmcnt incl. sc0sc1 h stores
    if (tid == 0) {
      __hip_atomic_fetch_add(cnt, 1u, __ATOMIC_RELAXED, __HIP_MEMORY_SCOPE_AGENT);
      unsigned tgt = (unsigned)(s + 1) * NBLK_;
      while (__hip_atomic_load(cnt, __ATOMIC_RELAXED, __HIP_MEMORY_SCOPE_AGENT) < tgt)
        __builtin_amdgcn_s_sleep(1);
    }
    __syncthreads();
  }
}

// ============================ host launch ============================

extern "C" void kernel_launch(void* const* d_in, const int* in_sizes, int n_in,
                              void* d_out, int out_size, void* d_ws, size_t ws_size,
                              hipStream_t stream)
{
  const float* x    = (const float*)d_in[0];
  const float* Wih0 = (const float*)d_in[1];
  const float* bih0 = (const float*)d_in[2];
  const float* Whh0 = (const float*)d_in[3];
  const float* bhh0 = (const float*)d_in[4];
  const float* Wih1 = (const float*)d_in[5];
  const float* bih1 = (const float*)d_in[6];
  const float* Whh1 = (const float*)d_in[7];
  const float* bhh1 = (const float*)d_in[8];

  char* ws = (char*)d_ws;
  u16* Wb0   = (u16*)(ws + WB0_OFF);
  u16* Wb1   = (u16*)(ws + WB1_OFF);
  u16* xT    = (u16*)(ws + XT_OFF);
  u16* h0b   = (u16*)(ws + H0_OFF);
  u16* h1b   = (u16*)(ws + H1_OFF);
  float* bias = (float*)(ws + BIAS_OFF);
  unsigned* cnt = (unsigned*)(ws + CNT_OFF);
  float* out = (float*)d_out;

  prep_misc<<<512, 256, 0, stream>>>(bih0, bhh0, bih1, bhh1, bias, (u32*)h0b, cnt);
  prep_w<<<3584, 256, 0, stream>>>(Wih0, Whh0, Wih1, Whh1, Wb0, Wb1);
  prep_x<<<4096, 256, 0, stream>>>(x, xT);
  lstm_persist<<<NBLK_, NTHR_, 0, stream>>>(xT, Wb0, Wb1, h0b, h1b, bias, cnt, out);
}

// Round 2
// 16426.448 us; speedup vs baseline: 1.0141x; 1.0141x over previous
//
#include <hip/hip_runtime.h>
#include <hip/hip_bf16.h>
#include <stdint.h>

typedef unsigned short u16;
typedef unsigned int   u32;
typedef unsigned long long u64;
typedef __attribute__((ext_vector_type(4)))  int   i32x4;
typedef __attribute__((ext_vector_type(4)))  float f32x4;
typedef __attribute__((ext_vector_type(8)))  u16   u16x8;

#define B_    64
#define T_    512
#define DIN_  512
#define H_    1024
#define NBLK_ 128
#define NTHR_ 512

#define OUT_MAIN_ (64ull*512*1024)
#define HN_BASE_  OUT_MAIN_
#define CN_BASE_  (OUT_MAIN_ + 2ull*64*1024)

// ---- workspace layout (bytes) ----
#define WB0_OFF  0ull
#define WB0_SZ   (64ull*64*1536*2)
#define WB1_OFF  (WB0_OFF + WB0_SZ)
#define WB1_SZ   (64ull*64*2048*2)
#define XT_OFF   (WB1_OFF + WB1_SZ)
#define XT_SZ    (512ull*64*512*2)
#define H0_OFF   (XT_OFF + XT_SZ)
#define H0_SZ    (8ull*2*64*1024*2)      // [rep][par][b][h] bf16
#define H1_OFF   (H0_OFF + H0_SZ)
#define H1_SZ    H0_SZ
#define BIAS_OFF (H1_OFF + H1_SZ)
#define BIAS_SZ  (2ull*4096*4)
#define SYNC_OFF (BIAS_OFF + BIAS_SZ)

__device__ __forceinline__ u16 f2bf(float f) {   // RNE fp32 -> bf16
  u32 u = __builtin_bit_cast(u32, f);
  return (u16)((u + 0x7FFFu + ((u >> 16) & 1u)) >> 16);
}
__device__ __forceinline__ float sigf(float x) {
  float e = __builtin_amdgcn_exp2f(x * -1.442695041f);
  return __builtin_amdgcn_rcpf(1.0f + e);
}
__device__ __forceinline__ float tanhf_fast(float x) {
  float e = __builtin_amdgcn_exp2f(x * -2.885390082f);
  float r = __builtin_amdgcn_rcpf(1.0f + e);
  return fmaf(2.0f, r, -1.0f);
}

#define VMW(n) asm volatile("s_waitcnt vmcnt(" #n ")" ::: "memory")
#define GLOAD(dst, a)   asm volatile("global_load_dwordx4 %0, %1, off"         : "=v"(dst) : "v"(a))
#define GLOADC(dst, a)  asm volatile("global_load_dwordx4 %0, %1, off sc0 sc1" : "=v"(dst) : "v"(a))

// ============================ prep kernels ============================

__global__ void prep_misc(const float* __restrict__ bih0, const float* __restrict__ bhh0,
                          const float* __restrict__ bih1, const float* __restrict__ bhh1,
                          float* __restrict__ bias, u32* __restrict__ hz,
                          u32* __restrict__ sync)
{
  int i = blockIdx.x * 256 + threadIdx.x;        // grid 4096*256 = 1,048,576
  if (i < 4096) bias[i] = bih0[i] + bhh0[i];
  else if (i < 8192) bias[i] = bih1[i - 4096] + bhh1[i - 4096];
  if (i < 1048576) hz[i] = 0u;                   // zero all h replicas (4 MB)
  if (i < 256) sync[i] = 0u;
}

// transpose-gather weights: W[k][n] fp32 -> Wb[grp][col][K] bf16 (col-major slices)
__global__ void prep_w(const float* __restrict__ Wih0, const float* __restrict__ Whh0,
                       const float* __restrict__ Wih1, const float* __restrict__ Whh1,
                       u16* __restrict__ Wb0, u16* __restrict__ Wb1)
{
  __shared__ u16 tile[64][72];
  const int bid = blockIdx.x;
  const int layer = (bid >= 1536) ? 1 : 0;
  const int lb = layer ? bid - 1536 : bid;
  const int nkt = layer ? 32 : 24;
  const int kt = lb % nkt, nt = lb / nkt;
  const int K = layer ? 2048 : 1536;
  const int xlen = layer ? 1024 : 512;
  const float* Wih = layer ? Wih1 : Wih0;
  const float* Whh = layer ? Whh1 : Whh0;
  u16* Wb = layer ? Wb1 : Wb0;
  const int k0 = kt * 64, n0 = nt * 64;
  const int t = threadIdx.x;
  {
    int kr = t >> 2, ncs = (t & 3) * 16;
    int kk = k0 + kr;
    const float* src = (kk < xlen) ? (Wih + (size_t)kk * 4096)
                                   : (Whh + (size_t)(kk - xlen) * 4096);
    const float* p = src + n0 + ncs;
#pragma unroll
    for (int v = 0; v < 4; ++v) {
      f32x4 f = *(const f32x4*)(p + v * 4);
#pragma unroll
      for (int e = 0; e < 4; ++e) tile[kr][ncs + v*4 + e] = f2bf(f[e]);
    }
  }
  __syncthreads();
  {
    int c = t >> 2;
    int n = n0 + c;
    int gate = n >> 10, hcol = n & 1023;
    int grp = hcol >> 4, cd = gate * 16 + (hcol & 15);
    u16* dstc = Wb + ((size_t)(grp * 64 + cd) * K + k0);
#pragma unroll
    for (int kv = 0; kv < 2; ++kv) {
      int k8 = (t & 3) + 4 * kv;
      u16x8 vv;
#pragma unroll
      for (int e = 0; e < 8; ++e) vv[e] = tile[k8*8 + e][c];
      *(u16x8*)(dstc + k8 * 8) = vv;
    }
  }
}

// x [b][t][d] fp32 -> xT [t][b][d] bf16
__global__ void prep_x(const float* __restrict__ x, u16* __restrict__ xT)
{
  int i = blockIdx.x * 256 + threadIdx.x;
  int d16 = (i & 31) << 4;
  int b   = (i >> 5) & 63;
  int tt  = i >> 11;
  const float* s = x + ((size_t)b * T_ + tt) * DIN_ + d16;
  u16* d = xT + ((size_t)tt * B_ + b) * DIN_ + d16;
  f32x4 fa = *(const f32x4*)(s);
  f32x4 fb = *(const f32x4*)(s + 4);
  f32x4 fc = *(const f32x4*)(s + 8);
  f32x4 fd = *(const f32x4*)(s + 12);
  u16x8 o0, o1;
#pragma unroll
  for (int e = 0; e < 4; ++e) {
    o0[e] = f2bf(fa[e]); o0[4+e] = f2bf(fb[e]);
    o1[e] = f2bf(fc[e]); o1[4+e] = f2bf(fd[e]);
  }
  *(u16x8*)d = o0;
  *(u16x8*)(d + 8) = o1;
}

// ============================ persistent LSTM kernel ============================
// 128 blocks x 512 threads (1/CU). Blocks 0..63: layer0 (t=s); 64..127: layer1 (t=s-1).
// Block: 64 gate-cols x 64 batch rows. 8 waves = 2 row-jobs x 4 K-quarters.
// Wave: 32 rows x 64 cols, K/4 via k64 slices; MFMA 16x16x32; A coherent (sc0sc1,
// replica bid&7), x & B plain cached (B L2-resident). Ring-3 pipeline, vmcnt(24).
// K-reduction + gate exchange via LDS; h broadcast written to 8 replicas.

template<int LAYER>
__device__ __forceinline__ void phase(
    const int t, const int lane, const int w, const int grp, const int tid,
    const u16* __restrict__ xt, const u16* __restrict__ Wb,
    const u16* __restrict__ h0r, const u16* __restrict__ h1p,
    u16* __restrict__ hwbase, const int par,
    const float b0, const float b1, const float b2, const float b3,
    float (&cst)[2], float* __restrict__ out, float* exch1, float* exch2)
{
  constexpr int K  = LAYER ? 2048 : 1536;
  constexpr int NS = LAYER ? 8 : 6;              // k64 slices per wave (K/4/64)
  const int rj = w >> 2, kq = w & 3;
  const int l15 = lane & 15, lg = lane >> 4;
  const int r0 = rj * 32 + l15;
  const int klane = lg * 8;
  const char* wbj = (const char*)Wb;

  i32x4 rA[3][2][2];
  i32x4 rB[3][4][2];
  f32x4 acc[2][4] = {};

  auto LA = [&](int j) {
    int k0 = (kq + 4 * j) * 64;
    const char* base; int rs, kl; bool xs = false;
    if (LAYER == 0) {
      if (k0 < 512) { base = (const char*)xt;  rs = 512;  kl = k0;        xs = true; }
      else          { base = (const char*)h0r; rs = 1024; kl = k0 - 512; }
    } else {
      if (k0 < 1024){ base = (const char*)h0r; rs = 1024; kl = k0; }
      else          { base = (const char*)h1p; rs = 1024; kl = k0 - 1024; }
    }
    if (xs) {
#pragma unroll
      for (int m = 0; m < 2; ++m)
#pragma unroll
        for (int kh = 0; kh < 2; ++kh) {
          u64 a = (u64)(base + ((size_t)(r0 + 16*m) * rs + kl + 32*kh + klane) * 2);
          GLOAD(rA[j % 3][m][kh], a);
        }
    } else {
#pragma unroll
      for (int m = 0; m < 2; ++m)
#pragma unroll
        for (int kh = 0; kh < 2; ++kh) {
          u64 a = (u64)(base + ((size_t)(r0 + 16*m) * rs + kl + 32*kh + klane) * 2);
          GLOADC(rA[j % 3][m][kh], a);
        }
    }
  };
  auto LB = [&](int j) {
    int k0 = (kq + 4 * j) * 64;
#pragma unroll
    for (int n = 0; n < 4; ++n)
#pragma unroll
      for (int kh = 0; kh < 2; ++kh) {
        u64 a = (u64)(wbj + ((size_t)(l15 + 16*n) * K + k0 + 32*kh + klane) * 2);
        GLOAD(rB[j % 3][n][kh], a);
      }
  };

  LA(0); LB(0); LA(1); LB(1);
#pragma unroll
  for (int j = 0; j < NS; ++j) {
    if (j + 2 < NS) { LA(j + 2); LB(j + 2); }
    if (j + 2 < NS) { VMW(24); } else if (j + 1 < NS) { VMW(12); } else { VMW(0); }
    __builtin_amdgcn_sched_barrier(0);
#pragma unroll
    for (int m = 0; m < 2; ++m)
#pragma unroll
      for (int n = 0; n < 4; ++n)
#pragma unroll
        for (int kh = 0; kh < 2; ++kh)
          asm("v_mfma_f32_16x16x32_bf16 %0, %1, %2, %0"
              : "+v"(acc[m][n]) : "v"(rA[j % 3][m][kh]), "v"(rB[j % 3][n][kh]));
  }
  asm volatile("s_nop 7\n\ts_nop 7\n\ts_nop 7");   // mfma -> vgpr-read hazard pad

  // ---- K-quarter reduction: write partials [kq][col][row(+pad)] ----
  {
    float* e1 = exch1 + (size_t)kq * 64 * 68;
#pragma unroll
    for (int m = 0; m < 2; ++m)
#pragma unroll
      for (int n = 0; n < 4; ++n) {
        int c = 16 * n + l15;
        int r = rj * 32 + 16 * m + lg * 4;
        *(f32x4*)(e1 + (size_t)c * 68 + r) = acc[m][n];
      }
  }
  __syncthreads();
  // ---- stage1: sum 4 partials; thread: col=tid>>3, rows (tid&7)*8..+8 ----
  {
    int c1 = tid >> 3, rr = (tid & 7) * 8;
    f32x4 s0 = {0,0,0,0}, s1 = {0,0,0,0};
#pragma unroll
    for (int q = 0; q < 4; ++q) {
      const float* p = exch1 + ((size_t)q * 64 + c1) * 68 + rr;
      s0 += *(const f32x4*)p;
      s1 += *(const f32x4*)(p + 4);
    }
    *(f32x4*)(exch2 + (size_t)c1 * 68 + rr)     = s0;
    *(f32x4*)(exch2 + (size_t)c1 * 68 + rr + 4) = s1;
  }
  __syncthreads();
  // ---- cell update: thread = (hc=tid&15, rows tid>>4 and +32) ----
  {
    int hc = tid & 15, rb = tid >> 4;
    int colg = grp * 16 + hc;
#pragma unroll
    for (int e = 0; e < 2; ++e) {
      int row = rb + 32 * e;
      float g0 = exch2[(size_t)(0 * 16 + hc) * 68 + row];
      float g1 = exch2[(size_t)(1 * 16 + hc) * 68 + row];
      float g2 = exch2[(size_t)(2 * 16 + hc) * 68 + row];
      float g3 = exch2[(size_t)(3 * 16 + hc) * 68 + row];
      float ig = sigf(g0 + b0);
      float fg = sigf(g1 + b1);
      float cg = fmaxf(g2 + b2, 0.0f);
      float og = sigf(g3 + b3);
      float cn = fg * cst[e] + ig * cg;
      cst[e] = cn;
      float h = og * tanhf_fast(cn);
      u32 hb = (u32)f2bf(h);
#pragma unroll
      for (int rep = 0; rep < 8; ++rep) {
        u64 a = (u64)((const char*)hwbase + (((size_t)(rep * 2 + par) * 64 + row) * 1024 + colg) * 2);
        asm volatile("global_store_short %0, %1, off sc0 sc1" :: "v"(a), "v"(hb) : "memory");
      }
      if (LAYER == 1) out[((size_t)row * T_ + t) * H_ + colg] = h;
      if (t == T_ - 1) {
        out[HN_BASE_ + ((size_t)LAYER * 64 + row) * H_ + colg] = h;
        out[CN_BASE_ + ((size_t)LAYER * 64 + row) * H_ + colg] = cn;
      }
    }
  }
}

__global__ __launch_bounds__(NTHR_, 2) void lstm_persist(
    const u16* __restrict__ xT, const u16* __restrict__ Wb0, const u16* __restrict__ Wb1,
    u16* __restrict__ h0b, u16* __restrict__ h1b, const float* __restrict__ bias,
    u32* __restrict__ sync, float* __restrict__ out)
{
  __shared__ __align__(16) float exch1[4 * 64 * 68];
  __shared__ __align__(16) float exch2[64 * 68];
  const int tid = threadIdx.x, lane = tid & 63, w = tid >> 6;
  const int bid = blockIdx.x;
  const int layer = bid >> 6, grp = bid & 63;
  const int rep = bid & 7;
  const u16* Wb = layer ? (Wb1 + (size_t)grp * 64 * 2048) : (Wb0 + (size_t)grp * 64 * 1536);
  float b0, b1, b2, b3;
  {
    int colg = grp * 16 + (tid & 15);
    const float* bb = bias + layer * 4096;
    b0 = bb[colg]; b1 = bb[1024 + colg]; b2 = bb[2048 + colg]; b3 = bb[3072 + colg];
  }
  float cst[2] = {0.f, 0.f};

  for (int s = 0; s <= T_; ++s) {
    if (layer == 0) {
      if (s < T_) {
        const u16* h0r = h0b + ((size_t)(rep * 2 + ((s + 1) & 1))) * 65536;
        phase<0>(s, lane, w, grp, tid, xT + (size_t)s * B_ * DIN_, Wb,
                 h0r, nullptr, h0b, s & 1, b0, b1, b2, b3, cst, out, exch1, exch2);
      }
    } else {
      if (s >= 1) {
        const u16* h0r = h0b + ((size_t)(rep * 2 + ((s + 1) & 1))) * 65536;
        const u16* h1p = h1b + ((size_t)(rep * 2 + (s & 1))) * 65536;
        phase<1>(s - 1, lane, w, grp, tid, nullptr, Wb,
                 h0r, h1p, h1b, (s + 1) & 1, b0, b1, b2, b3, cst, out, exch1, exch2);
      }
    }
    // ---- tree grid barrier: 8 leaves x16 -> root -> broadcast flag ----
    asm volatile("s_waitcnt vmcnt(0)" ::: "memory");
    __syncthreads();
    if (tid == 0) {
      u32* leaf = sync + (bid >> 4) * 16;
      u32 old = __hip_atomic_fetch_add(leaf, 1u, __ATOMIC_RELAXED, __HIP_MEMORY_SCOPE_AGENT);
      if (old == (u32)s * 16u + 15u) {
        u32 r = __hip_atomic_fetch_add(sync + 128, 1u, __ATOMIC_RELAXED, __HIP_MEMORY_SCOPE_AGENT);
        if (r == (u32)s * 8u + 7u)
          __hip_atomic_store(sync + 144, (u32)(s + 1), __ATOMIC_RELAXED, __HIP_MEMORY_SCOPE_AGENT);
      }
      while (__hip_atomic_load(sync + 144, __ATOMIC_RELAXED, __HIP_MEMORY_SCOPE_AGENT) < (u32)(s + 1))
        __builtin_amdgcn_s_sleep(2);
    }
    __syncthreads();
  }
}

// ============================ host launch ============================

extern "C" void kernel_launch(void* const* d_in, const int* in_sizes, int n_in,
                              void* d_out, int out_size, void* d_ws, size_t ws_size,
                              hipStream_t stream)
{
  const float* x    = (const float*)d_in[0];
  const float* Wih0 = (const float*)d_in[1];
  const float* bih0 = (const float*)d_in[2];
  const float* Whh0 = (const float*)d_in[3];
  const float* bhh0 = (const float*)d_in[4];
  const float* Wih1 = (const float*)d_in[5];
  const float* bih1 = (const float*)d_in[6];
  const float* Whh1 = (const float*)d_in[7];
  const float* bhh1 = (const float*)d_in[8];

  char* ws = (char*)d_ws;
  u16* Wb0    = (u16*)(ws + WB0_OFF);
  u16* Wb1    = (u16*)(ws + WB1_OFF);
  u16* xT     = (u16*)(ws + XT_OFF);
  u16* h0b    = (u16*)(ws + H0_OFF);
  u16* h1b    = (u16*)(ws + H1_OFF);
  float* bias = (float*)(ws + BIAS_OFF);
  u32* sync   = (u32*)(ws + SYNC_OFF);
  float* out  = (float*)d_out;

  prep_misc<<<4096, 256, 0, stream>>>(bih0, bhh0, bih1, bhh1, bias, (u32*)h0b, sync);
  prep_w<<<3584, 256, 0, stream>>>(Wih0, Whh0, Wih1, Whh1, Wb0, Wb1);
  prep_x<<<4096, 256, 0, stream>>>(x, xT);
  lstm_persist<<<NBLK_, NTHR_, 0, stream>>>(xT, Wb0, Wb1, h0b, h1b, bias, sync, out);
}